// Round 12
// baseline (12890.997 us; speedup 1.0000x reference)
//
#include <hip/hip_runtime.h>
#include <stdint.h>
#include <string.h>
#include <math.h>

// DCRNN forward on MI355X. Runtime dtype detection (fp32 vs bf16) via enc0_bg==ones.
// Phase 0/1 (weight prep, fc_his, diffusion P1..P4) = discrete kernels (as round 10).
// Phase 2 (the 48-cell RNN) = ONE persistent mega-kernel: 256 blocks x 512 thr,
// 96 KB static LDS -> exactly 1 block/CU -> all 256 blocks co-resident (capacity
// guarantee, no cooperative API). Stages separated by device-scope monotonic flag
// barriers (threadfence + relaxed flag store/spin + threadfence = cross-XCD visibility).
// GEMM bodies identical math to round 10 (k-order preserved -> bitwise-same absmax).

using bfrag = __attribute__((__ext_vector_type__(8))) short;
using accv  = __attribute__((__ext_vector_type__(4))) float;

#define DEVI static __device__ __forceinline__

DEVI float bf2f(short x) {
  union { unsigned u; float f; } v; v.u = ((unsigned)(unsigned short)x) << 16; return v.f;
}
DEVI short f2bf(float f) {
  union { float f; unsigned u; } v; v.f = f;
  unsigned r = v.u + 0x7FFFu + ((v.u >> 16) & 1u);
  return (short)(r >> 16);
}
DEVI float ldx(const void* p, long i, int f32) {
  return f32 ? ((const float*)p)[i] : bf2f(((const short*)p)[i]);
}
DEVI void gl16(const short* g, short* l) {  // 16B direct global->LDS (dest = base + lane*16)
  __builtin_amdgcn_global_load_lds(
      (const __attribute__((address_space(1))) void*)g,
      (__attribute__((address_space(3))) void*)l, 16, 0, 0);
}

struct GP {
  const short* A;  long sA;  int lda;    // A: (M x K) row-major per batch (bf16 internal)
  const short* BT; long sBT; int ldbt;   // B transposed: (N x K) row-major per batch
  int K;
  short* C; long sC; int ldc;            // EPI 0/1 normal store
  short* CT;                             // EPI 2: plain transpose store; EPI 3: VT scatter
  const void* bias;
  const short* V0;                       // VT base (identity term) for EPI 4/5
  const int* flg;
  int outDim, oshift;
  int mtiles;                            // SWZ=1 wrapper only
  const float* h; float* hw; const float* u;
  short* xc; int inpOff;                 // EPI4: Xc target (r*h), state col offset
  short* xgs; int xgsOff;                // EPI5 persistent-X maintenance
  short* xch;
  short* nxg; short* nxc;
  const void* hsrc; long hoff;
};

// Generic tile body: BM x BN, BK k-slab, THR threads, PIPE-stage LDS pipeline.
// EPI: 0 plain; 1 bias+relu; 2 +transposed copy; 3 VT scatter; 4 gate; 5 cand.
template<int EPI, int BM, int BN, int BK, int THR, int PIPE>
DEVI void gemm_body(const GP& p, int m0, int n0, int bz, short* lds, int f32) {
  constexpr int W    = THR / 64;
  constexpr int WROW = BM / 32;
  constexpr int WCOL = (W / WROW < 1) ? 1 : W / WROW;
  constexpr int NT   = BN / (16 * WCOL);
  constexpr int CH   = BK / 8;
  constexpr int AI   = (BM * CH) / THR;
  constexpr int BI   = (BN * CH) / THR;
  constexpr int LD   = AI + BI;
  constexpr int TB   = (BM + BN) * BK;
  constexpr int ST   = BM + 8;                  // transpose LDS stride
  const int tid  = threadIdx.x;
  const int w    = tid >> 6;
  const int lane = tid & 63;
  const int quad = lane >> 4, l16 = lane & 15;
  const int rowW = (w % WROW) * 32;
  const int colW = (w / WROW) * (NT * 16);

  const short* Ab = p.A  + (long)bz * p.sA + m0 * (long)p.lda;
  const short* Bb = p.BT + (long)bz * p.sBT + n0 * (long)p.ldbt;

  accv acc[2][NT];
#pragma unroll
  for (int i = 0; i < 2; i++)
#pragma unroll
    for (int j = 0; j < NT; j++) { accv z = {0.f,0.f,0.f,0.f}; acc[i][j] = z; }

  const short* asrc[AI]; int aoff[AI];
#pragma unroll
  for (int i = 0; i < AI; i++) {
    const int s = (w*AI + i)*64 + lane;
    const int r = s / CH, c = (s % CH) ^ (r & 7);
    asrc[i] = Ab + (long)r * p.lda + c*8;
    aoff[i] = (w*AI + i)*512;
  }
  const short* bsrc[BI]; int boff[BI];
#pragma unroll
  for (int i = 0; i < BI; i++) {
    const int s = (w*BI + i)*64 + lane;
    const int r = s / CH, c = (s % CH) ^ (r & 7);
    bsrc[i] = Bb + (long)r * p.ldbt + c*8;
    boff[i] = BM*BK + (w*BI + i)*512;
  }

  const int nIter = p.K / BK;
#pragma unroll
  for (int s = 0; s < PIPE-1; ++s) {
    if (s < nIter) {
      const int kk = s * BK;
#pragma unroll
      for (int i = 0; i < AI; i++) gl16(asrc[i] + kk, &lds[s*TB + aoff[i]]);
#pragma unroll
      for (int i = 0; i < BI; i++) gl16(bsrc[i] + kk, &lds[s*TB + boff[i]]);
    }
  }

  for (int it = 0; it < nIter; ++it) {
    const int bufO = (it & (PIPE-1)) * TB;
    if (it + PIPE - 1 < nIter) {
      const int nxt = ((it + PIPE - 1) & (PIPE-1)) * TB;
      const int kk = (it + PIPE - 1) * BK;
#pragma unroll
      for (int i = 0; i < AI; i++) gl16(asrc[i] + kk, &lds[nxt + aoff[i]]);
#pragma unroll
      for (int i = 0; i < BI; i++) gl16(bsrc[i] + kk, &lds[nxt + boff[i]]);
    }
    const int rem = nIter - 1 - it;
    if (rem >= PIPE-1)   __builtin_amdgcn_s_waitcnt(0xF70 | ((PIPE-1)*LD));
    else if (rem == 2)   __builtin_amdgcn_s_waitcnt(0xF70 | (2*LD));
    else if (rem == 1)   __builtin_amdgcn_s_waitcnt(0xF70 | (1*LD));
    else                 __builtin_amdgcn_s_waitcnt(0xF70);
    asm volatile("s_barrier" ::: "memory");
#pragma unroll
    for (int ks = 0; ks < BK; ks += 32) {
      const int ch = (ks >> 3) + quad;
      bfrag fa[2];
#pragma unroll
      for (int rt = 0; rt < 2; rt++) {
        const int ar = rowW + rt*16 + l16;
        fa[rt] = *(const bfrag*)&lds[bufO + (ar*CH + (ch ^ (ar & 7))) * 8];
      }
#pragma unroll
      for (int nt = 0; nt < NT; nt++) {
        const int br = colW + nt*16 + l16;
        bfrag fb = *(const bfrag*)&lds[bufO + BM*BK + (br*CH + (ch ^ (br & 7))) * 8];
        acc[0][nt] = __builtin_amdgcn_mfma_f32_16x16x32_bf16(fa[0], fb, acc[0][nt], 0, 0, 0);
        acc[1][nt] = __builtin_amdgcn_mfma_f32_16x16x32_bf16(fa[1], fb, acc[1][nt], 0, 0, 0);
      }
    }
    asm volatile("s_barrier" ::: "memory");
  }

  if constexpr (EPI == 0 || EPI == 1 || EPI == 2) {
#pragma unroll
    for (int rt = 0; rt < 2; rt++) {
      const int rbase = m0 + rowW + rt*16 + quad*4;
#pragma unroll
      for (int nt = 0; nt < NT; nt++) {
        const int cc = n0 + colW + nt*16 + l16;
#pragma unroll
        for (int e = 0; e < 4; e++) {
          float val = acc[rt][nt][e];
          if constexpr (EPI == 1) { val += ldx(p.bias, cc, f32); val = val > 0.f ? val : 0.f; }
          p.C[(long)bz * p.sC + (long)(rbase + e) * p.ldc + cc] = f2bf(val);
        }
      }
    }
  }
  if constexpr (EPI == 2 || EPI == 3) {
    constexpr int TPC = THR / BN;            // threads per output column
    constexpr int SEG = BM / TPC;            // shorts per thread segment
    __syncthreads();
#pragma unroll
    for (int rt = 0; rt < 2; rt++)
#pragma unroll
      for (int nt = 0; nt < NT; nt++)
#pragma unroll
        for (int e = 0; e < 4; e++)
          lds[(colW + nt*16 + l16)*ST + (rowW + rt*16 + quad*4 + e)] = f2bf(acc[rt][nt][e]);
    __syncthreads();
    const int c = tid / TPC, seg = tid % TPC;
    const int cG = n0 + c;
    const short* sp = &lds[c*ST + seg*SEG];
    long dst;
    if constexpr (EPI == 3) {
      const int m  = cG >> p.oshift;
      const int o  = cG & (p.outDim - 1);
      const int bb = m0 >> 9;
      dst = ((long)((bb * p.outDim + o) * 5 + m) << 9) + (m0 & 511) + seg*SEG;
    } else {
      dst = (((long)bz << 9) + cG) * 512 + m0 + seg*SEG;
    }
    short* dp = p.CT + dst;
#pragma unroll
    for (int s2 = 0; s2 < SEG/8; s2++)
      *(bfrag*)(dp + s2*8) = *(const bfrag*)(sp + s2*8);
  }
  if constexpr (EPI == 4) {  // gate: sigmoid; o<64 -> Xc = r*h ; o>=64 -> u
#pragma unroll
    for (int rt = 0; rt < 2; rt++) {
      const int nb = m0 + rowW + rt*16 + quad*4;
#pragma unroll
      for (int nt = 0; nt < NT; nt++) {
        const int o = n0 + colW + nt*16 + l16;
        const float bv = ldx(p.bias, o, f32);
#pragma unroll
        for (int e = 0; e < 4; e++) {
          const int nn = nb + e;
          float val = acc[rt][nt][e] + bv +
                      bf2f(p.V0[(long)(bz * p.outDim + o) * 2560 + nn]);
          const float s = 1.f / (1.f + __expf(-val));
          const long bn = ((long)bz << 9) + nn;
          if (o < 64) p.xc[bn*128 + p.inpOff + o] = f2bf(s * p.h[(bn << 6) + o]);
          else        p.hw[(bn << 6) + (o - 64)] = s;
        }
      }
    }
  }
  if constexpr (EPI == 5) {  // cand: tanh; h = u*h + (1-u)*c; maintain persistent X bufs
#pragma unroll
    for (int rt = 0; rt < 2; rt++) {
      const int nb = m0 + rowW + rt*16 + quad*4;
#pragma unroll
      for (int nt = 0; nt < NT; nt++) {
        const int o = n0 + colW + nt*16 + l16;
        const float bv = ldx(p.bias, o, f32);
#pragma unroll
        for (int e = 0; e < 4; e++) {
          const int nn = nb + e;
          float val = acc[rt][nt][e] + bv +
                      bf2f(p.V0[(long)(bz * p.outDim + o) * 2560 + nn]);
          const float cth = tanhf(val);
          const long bn = ((long)bz << 9) + nn;
          const long idx = bn*64 + o;
          const float uo = p.u[idx];
          const float hn = uo * p.h[idx] + (1.f - uo) * cth;
          p.hw[idx] = hn;
          const short hb = f2bf(hn);
          if (p.xgs) p.xgs[bn*128 + p.xgsOff + o] = hb;
          if (p.nxg) { p.nxg[bn*128 + o] = hb; p.nxc[bn*128 + o] = hb; }
          if (p.hsrc != nullptr && o < 2) {
            const short hv = f2bf(ldx(p.hsrc, p.hoff + (long)bz*12288 + (long)nn*2 + o, f32));
            p.xgs[bn*128 + o] = hv;
            p.xch[bn*128 + o] = hv;
          }
        }
      }
    }
  }
}

// standalone wrapper (phases 0/1)
template<int EPI, int BM, int BN, int BK, int THR, int SWZ, int PIPE>
__global__ __launch_bounds__(THR)
void gemm_k(GP p) {
  constexpr int TB  = (BM + BN) * BK;
  constexpr int LSZ = (PIPE*TB > BN*(BM+8)) ? PIPE*TB : BN*(BM+8);
  __shared__ __align__(16) short lds[LSZ];
  int m0, n0, bz;
  if constexpr (SWZ == 1) {
    const int blk = blockIdx.x;
    bz = blk & 31;
    const int tile = blk >> 5;
    m0 = (tile % p.mtiles) * BM;
    n0 = (tile / p.mtiles) * BN;
  } else {
    m0 = blockIdx.x * BM; n0 = blockIdx.y * BN; bz = blockIdx.z;
  }
  int f32 = 0;
  if constexpr (EPI == 1 || EPI == 4 || EPI == 5) f32 = *p.flg;
  gemm_body<EPI,BM,BN,BK,THR,PIPE>(p, m0, n0, bz, lds, f32);
}

// ---- RNN mega-kernel ----

struct MK {
  const short* Pbig;
  const short* wctg[4]; const short* wctc[4];
  const void* bg[4]; const void* bc[4];
  short* VTg; short* VTc;
  short* Xg0; short* Xc0; short* Xg1; short* Xc1;
  float* ub; float* h0; float* h1;
  const short* hisb;
  const void* hist; const void* projW; const void* projb;
  void* dout;
  int* flags; const int* flg;
};

__global__ __launch_bounds__(512)
void rnn_mega(MK mk) {
  __shared__ __align__(16) short lds[49152];   // 96 KB -> 1 block/CU -> co-residency
  const int blk = blockIdx.x, tid = threadIdx.x;
  const int f32 = *mk.flg;
  int gen = 0;

  auto bar = [&]() {
    ++gen;
    __syncthreads();
    if (tid == 0) {
      __threadfence();  // release: all prior stores visible agent-wide
      __hip_atomic_store(&mk.flags[blk], gen, __ATOMIC_RELAXED, __HIP_MEMORY_SCOPE_AGENT);
    }
    if (tid < 256) {
      while (__hip_atomic_load(&mk.flags[tid], __ATOMIC_RELAXED,
                               __HIP_MEMORY_SCOPE_AGENT) < gen)
        __builtin_amdgcn_s_sleep(2);
    }
    __threadfence();    // acquire: invalidate caches before reading others' data
    __syncthreads();
  };

  auto cell = [&](int wi, int inpOff, float* hstate, short* XgL, short* XcL,
                  short* nxg, short* nxc, const void* hsrc, long hoff) {
    GP q;
    // g1: XgL(16384x128) @ WcatT -> VTg scatter. 1280 tiles (128mt x 10nt), 5/block.
    q = GP{}; q.A = XgL; q.lda = 128; q.BT = mk.wctg[wi]; q.ldbt = 128; q.K = 128;
    q.CT = mk.VTg; q.outDim = 128; q.oshift = 7;
    for (int i = 0; i < 5; i++) {
      const int tile = i*256 + blk;
      gemm_body<3,128,64,64,512,2>(q, (tile & 127)*128, (tile >> 7)*64, 0, lds, 0);
      __syncthreads();
    }
    bar();
    // g2: Pbig @ Ug (K=2048) fused sigmoid. 256 tiles (8mt x 32bz), 1/block, PIPE=4.
    q = GP{}; q.A = mk.Pbig; q.sA = 512*2048; q.lda = 2048;
    q.BT = mk.VTg + 512; q.sBT = 128*2560; q.ldbt = 2560; q.K = 2048;
    q.V0 = mk.VTg; q.outDim = 128; q.bias = mk.bg[wi];
    q.h = hstate; q.hw = mk.ub; q.xc = XcL; q.inpOff = inpOff;
    gemm_body<4,64,128,64,512,4>(q, (blk >> 5)*64, 0, blk & 31, lds, f32);
    bar();
    // c1: XcL @ WcT -> VTc scatter. 1280 tiles (256mt x 5nt), 5/block.
    q = GP{}; q.A = XcL; q.lda = 128; q.BT = mk.wctc[wi]; q.ldbt = 128; q.K = 128;
    q.CT = mk.VTc; q.outDim = 64; q.oshift = 6;
    for (int i = 0; i < 5; i++) {
      const int tile = i*256 + blk;
      gemm_body<3,64,64,64,512,2>(q, (tile & 255)*64, (tile >> 8)*64, 0, lds, 0);
      __syncthreads();
    }
    bar();
    // c2: Pbig @ Uc (K=2048) fused tanh + h update. 256 tiles, 1/block, PIPE=4.
    q = GP{}; q.A = mk.Pbig; q.sA = 512*2048; q.lda = 2048;
    q.BT = mk.VTc + 512; q.sBT = 64*2560; q.ldbt = 2560; q.K = 2048;
    q.V0 = mk.VTc; q.outDim = 64; q.bias = mk.bc[wi];
    q.h = hstate; q.hw = hstate; q.u = mk.ub;
    q.xgs = XgL; q.xgsOff = inpOff; q.xch = XcL;
    q.nxg = nxg; q.nxc = nxc; q.hsrc = hsrc; q.hoff = hoff;
    gemm_body<5,64,64,64,512,4>(q, (blk >> 5)*64, 0, blk & 31, lds, f32);
    bar();
  };

  // encoder
  for (int t = 0; t < 12; t++) {
    cell(0, 2, mk.h0, mk.Xg0, mk.Xc0, mk.Xg1, mk.Xc1,
         (t < 11) ? mk.hist : nullptr, (long)(t + 1) * 1024);
    cell(1, 64, mk.h1, mk.Xg1, mk.Xc1, nullptr, nullptr, nullptr, 0);
  }
  // his_add
  for (int i = blk*512 + tid; i < 1048576; i += 131072) {
    const int row = i >> 6, o = i & 63;
    const float v = bf2f(mk.hisb[i]);
    const float a = mk.h0[i] + v, b = mk.h1[i] + v;
    mk.h0[i] = a; mk.h1[i] = b;
    mk.Xg0[(long)row*128 + 1 + o]  = f2bf(a);
    mk.Xg1[(long)row*128 + 64 + o] = f2bf(b);
    if (o == 0) { mk.Xg0[(long)row*128] = 0; mk.Xc0[(long)row*128] = 0; }
  }
  bar();
  // decoder
  const int lane = tid & 63;
  const int wid  = (blk*512 + tid) >> 6;   // 0..2047
  for (int t = 0; t < 12; t++) {
    cell(2, 1, mk.h0, mk.Xg0, mk.Xc0, mk.Xg1, mk.Xc1, nullptr, 0);
    cell(3, 64, mk.h1, mk.Xg1, mk.Xc1, nullptr, nullptr, nullptr, 0);
    // proj: wave-per-row
    for (int row = wid; row < 16384; row += 2048) {
      float v = mk.h1[((long)row << 6) + lane] * ldx(mk.projW, lane, f32);
      for (int off = 32; off > 0; off >>= 1) v += __shfl_down(v, off, 64);
      if (lane == 0) {
        const float s = v + ldx(mk.projb, 0, f32);
        if (f32) ((float*)mk.dout)[row*12 + t] = s;
        else     ((short*)mk.dout)[row*12 + t] = f2bf(s);
        const short o = f2bf(s);
        mk.Xg0[(long)row*128] = o;
        mk.Xc0[(long)row*128] = o;
      }
    }
    bar();
  }
}

// ---- small kernels ----

__global__ void detect_k(const short* bg0, int* flag) {
  if (threadIdx.x == 0 && blockIdx.x == 0)
    *flag = (bg0[0] == (short)0x3F80) ? 0 : 1;
}

__global__ void rowsum_inv(const void* adj, const int* flg, float* rsi) {
  const int f32 = *flg;
  const int wid  = (blockIdx.x * 256 + threadIdx.x) >> 6;
  const int lane = threadIdx.x & 63;
  const long base = (long)wid * 512;
  float s = 0.f;
  for (int j = lane; j < 512; j += 64) s += ldx(adj, base + j, f32);
  for (int off = 32; off > 0; off >>= 1) s += __shfl_down(s, off, 64);
  if (lane == 0) rsi[wid] = 1.f / (1.f + s);
}

__global__ void colsum_inv(const void* adj, const int* flg, float* csi) {
  const int f32 = *flg;
  const int i = blockIdx.x * 256 + threadIdx.x;
  const int b = i >> 9, col = i & 511;
  const long base = (long)b * 262144 + col;
  float s = 1.f;
  for (int j = 0; j < 512; j++) s += ldx(adj, base + (long)j * 512, f32);
  csi[i] = 1.f / s;
}

__global__ __launch_bounds__(256)
void build_a(const void* adj, const int* flg, const float* rsi, const float* csi,
             short* Pbig, short* A1T, short* A2) {
  const int f32 = *flg;
  __shared__ __align__(16) float t[64 * 65];
  const int b = blockIdx.z, ti = blockIdx.x, tj = blockIdx.y;
  const int tid = threadIdx.x;
  const int r = tid >> 2, cs = (tid & 3) * 16;
  const long base = (long)b * 262144 + (long)(ti*64 + r) * 512 + tj*64 + cs;
#pragma unroll
  for (int j = 0; j < 16; j++) t[r*65 + cs + j] = ldx(adj, base + j, f32);
  __syncthreads();
  {
    const int gi = ti*64 + r;
    const float inv = rsi[b*512 + gi];
    short o[16];
#pragma unroll
    for (int j = 0; j < 16; j++) {
      const int gj = tj*64 + cs + j;
      o[j] = f2bf((t[r*65 + cs + j] + (gi == gj ? 1.f : 0.f)) * inv);
    }
    short* dp = Pbig + ((long)(b*512 + gi) << 11) + tj*64 + cs;
    bfrag v0 = {o[0],o[1],o[2],o[3],o[4],o[5],o[6],o[7]};
    bfrag v1 = {o[8],o[9],o[10],o[11],o[12],o[13],o[14],o[15]};
    *(bfrag*)dp = v0; *(bfrag*)(dp + 8) = v1;
  }
  {
    const int y = tj*64 + r;
    const float invc = csi[b*512 + y];
    short o1[16], o2[16];
#pragma unroll
    for (int j = 0; j < 16; j++) {
      const int x = ti*64 + cs + j;
      const float av = t[(cs + j)*65 + r];
      const float d = (x == y) ? 1.f : 0.f;
      o1[j] = f2bf((av + d) * rsi[b*512 + x]);
      o2[j] = f2bf((av + d) * invc);
    }
    short* d1 = A1T + ((long)(b*512 + y) << 9) + ti*64 + cs;
    short* d2 = A2  + ((long)(b*512 + y) << 9) + ti*64 + cs;
    bfrag a0 = {o1[0],o1[1],o1[2],o1[3],o1[4],o1[5],o1[6],o1[7]};
    bfrag a1 = {o1[8],o1[9],o1[10],o1[11],o1[12],o1[13],o1[14],o1[15]};
    bfrag b0 = {o2[0],o2[1],o2[2],o2[3],o2[4],o2[5],o2[6],o2[7]};
    bfrag b1 = {o2[8],o2[9],o2[10],o2[11],o2[12],o2[13],o2[14],o2[15]};
    *(bfrag*)d1 = a0; *(bfrag*)(d1 + 8) = a1;
    *(bfrag*)d2 = b0; *(bfrag*)(d2 + 8) = b1;
  }
}

__global__ void build_wcat(const void* W, const int* flg, short* WT, int f, int out) {
  const int f32 = *flg;
  const int i = blockIdx.x * 256 + threadIdx.x;
  if (i >= 5 * out * 128) return;
  const int feat = i & 127;
  const int mo = i >> 7;
  const int m = mo / out;
  const int o = mo - m * out;
  float v = 0.f;
  if (feat < f) {
    const long base = (long)feat * 5 * out;
    const float w0 = ldx(W, base + 0*out + o, f32);
    const float w1 = ldx(W, base + 1*out + o, f32);
    const float w2 = ldx(W, base + 2*out + o, f32);
    const float w3 = ldx(W, base + 3*out + o, f32);
    const float w4 = ldx(W, base + 4*out + o, f32);
    v = (m == 0) ? (w0 - w2) : (m == 1) ? (w1 - w4) : (m == 2) ? 2.f*w2
      : (m == 3) ? w3 : 2.f*w4;
  }
  WT[(long)mo * 128 + feat] = f2bf(v);
}

__global__ void build_fc1T(const void* W, const int* flg, short* WT) {
  const int f32 = *flg;
  const int i = blockIdx.x * 256 + threadIdx.x;
  const int o = i >> 7, k = i & 127;
  WT[i] = (k < 96) ? f2bf(ldx(W, (long)k*256 + o, f32)) : (short)0;
}
__global__ void build_fc2T(const void* W, const int* flg, short* WT) {
  const int f32 = *flg;
  const int i = blockIdx.x * 256 + threadIdx.x;
  const int o = i >> 8, k = i & 255;
  WT[i] = f2bf(ldx(W, (long)k*64 + o, f32));
}
__global__ void pack_hid(const void* hd, const int* flg, short* hp) {
  const int f32 = *flg;
  const int i = blockIdx.x * 256 + threadIdx.x;
  const int row = i >> 7, k = i & 127;
  hp[i] = (k < 96) ? f2bf(ldx(hd, (long)row*96 + k, f32)) : (short)0;
}

__global__ void seed_hist(const void* hist, const int* flg, short* Xg0, short* Xc0) {
  const int f32 = *flg;
  const int i = blockIdx.x * 256 + threadIdx.x;
  const int row = i >> 1, c = i & 1;
  const short v = f2bf(ldx(hist, (long)(row >> 9)*12288 + (long)(row & 511)*2 + c, f32));
  Xg0[(long)row*128 + c] = v;
  Xc0[(long)row*128 + c] = v;
}

extern "C" void kernel_launch(void* const* d_in, const int* in_sizes, int n_in,
                              void* d_out, int out_size, void* d_ws, size_t ws_size,
                              hipStream_t stream) {
  (void)in_sizes; (void)n_in; (void)out_size;
  const void* hist   = d_in[0];
  const void* hidden = d_in[1];
  const void* adj    = d_in[2];
  const void* Wg[4] = {d_in[3], d_in[7],  d_in[11], d_in[15]};
  const void* bg[4] = {d_in[4], d_in[8],  d_in[12], d_in[16]};
  const void* Wc[4] = {d_in[5], d_in[9],  d_in[13], d_in[17]};
  const void* bc[4] = {d_in[6], d_in[10], d_in[14], d_in[18]};
  const void* projW = d_in[19];
  const void* projb = d_in[20];
  const void* fc1W  = d_in[21];
  const void* fc1b  = d_in[22];
  const void* fc2W  = d_in[23];
  const void* fc2b  = d_in[24];

  char* wp = (char*)d_ws;
  auto alloc = [&](size_t bytes) { char* r = wp; wp += (bytes + 255) & ~(size_t)255; return r; };
  short* Pbig = (short*)alloc(32ull*512*2048*2);
  float* ub   = (float*)alloc(16384ull*64*4);
  float* h0   = (float*)alloc(16384ull*64*4);
  float* h1   = (float*)alloc(16384ull*64*4);
  short* hisb = (short*)alloc(16384ull*64*2);
  short* wctg[4]; for (int i = 0; i < 4; i++) wctg[i] = (short*)alloc(640*128*2);
  short* wctc[4]; for (int i = 0; i < 4; i++) wctc[i] = (short*)alloc(320*128*2);
  float* rsi = (float*)alloc(16384*4);
  float* csi = (float*)alloc(16384*4);
  int*   flg = (int*)alloc(256);
  int*   flags = (int*)alloc(2048);
  char* ubase = wp;
  short* hidp = (short*)ubase;
  short* mid  = (short*)(ubase + 4194304);
  short* fc1T = (short*)(ubase + 4194304 + 8388608);
  short* fc2T = (short*)(ubase + 4194304 + 8388608 + 65536);
  short* A1T  = (short*)ubase;
  short* A2   = (short*)(ubase + 16777216);
  short* P3T  = (short*)(ubase + 33554432);
  short* VTg  = (short*)ubase;
  short* VTc  = (short*)(ubase + 20971520);
  short* Xg0  = (short*)(ubase + 31457280);
  short* Xc0  = (short*)(ubase + 35651584);
  short* Xg1  = (short*)(ubase + 39845888);
  short* Xc1  = (short*)(ubase + 44040192);
  const size_t need = (size_t)(ubase - (char*)d_ws) + 48234496 + 2097152;
  if (ws_size < need) return;

  detect_k<<<1, 64, 0, stream>>>((const short*)bg[0], flg);
  (void)hipMemsetAsync(h0, 0, 16384ull*64*4, stream);
  (void)hipMemsetAsync(h1, 0, 16384ull*64*4, stream);
  (void)hipMemsetAsync(flags, 0, 2048, stream);

  // ---- phase 0: weight prep + fc_his ----
  const int fdim[4] = {66, 128, 65, 128};
  for (int i = 0; i < 4; i++) {
    build_wcat<<<320, 256, 0, stream>>>(Wg[i], flg, wctg[i], fdim[i], 128);
    build_wcat<<<160, 256, 0, stream>>>(Wc[i], flg, wctc[i], fdim[i], 64);
  }
  build_fc1T<<<128, 256, 0, stream>>>(fc1W, flg, fc1T);
  build_fc2T<<<64, 256, 0, stream>>>(fc2W, flg, fc2T);
  pack_hid<<<8192, 256, 0, stream>>>(hidden, flg, hidp);

  GP p;
  p = GP{}; p.A = hidp; p.lda = 128; p.BT = fc1T; p.ldbt = 128; p.K = 128;
  p.C = mid; p.ldc = 256; p.bias = fc1b; p.flg = flg;
  gemm_k<1,128,64,64,256,0,2><<<dim3(128, 4, 1), 256, 0, stream>>>(p);
  p = GP{}; p.A = mid; p.lda = 256; p.BT = fc2T; p.ldbt = 256; p.K = 256;
  p.C = hisb; p.ldc = 64; p.bias = fc2b; p.flg = flg;
  gemm_k<1,128,64,64,256,0,2><<<dim3(128, 1, 1), 256, 0, stream>>>(p);

  // ---- phase 1: diffusion matrices ----
  rowsum_inv<<<4096, 256, 0, stream>>>(adj, flg, rsi);
  colsum_inv<<<64, 256, 0, stream>>>(adj, flg, csi);
  build_a<<<dim3(8, 8, 32), 256, 0, stream>>>(adj, flg, rsi, csi, Pbig, A1T, A2);

  p = GP{}; p.A = Pbig; p.sA = 512*2048; p.lda = 2048;
  p.BT = A1T; p.sBT = 512*512; p.ldbt = 512; p.K = 512;
  p.C = Pbig + 512; p.sC = 512*2048; p.ldc = 2048; p.flg = flg;
  gemm_k<0,128,64,64,256,0,2><<<dim3(4, 8, 32), 256, 0, stream>>>(p);
  p = GP{}; p.A = A2; p.sA = 512*512; p.lda = 512;
  p.BT = A1T; p.sBT = 512*512; p.ldbt = 512; p.K = 512;
  p.C = Pbig + 1024; p.sC = 512*2048; p.ldc = 2048; p.CT = P3T; p.flg = flg;
  gemm_k<2,128,64,64,256,0,2><<<dim3(4, 8, 32), 256, 0, stream>>>(p);
  p = GP{}; p.A = A2; p.sA = 512*512; p.lda = 512;
  p.BT = P3T; p.sBT = 512*512; p.ldbt = 512; p.K = 512;
  p.C = Pbig + 1536; p.sC = 512*2048; p.ldc = 2048; p.flg = flg;
  gemm_k<0,128,64,64,256,0,2><<<dim3(4, 8, 32), 256, 0, stream>>>(p);

  // ---- phase 2: persistent RNN mega-kernel ----
  (void)hipMemsetAsync(Xg0, 0, 4ull*4194304, stream);
  seed_hist<<<128, 256, 0, stream>>>(hist, flg, Xg0, Xc0);

  MK mk{};
  mk.Pbig = Pbig;
  for (int i = 0; i < 4; i++) { mk.wctg[i] = wctg[i]; mk.wctc[i] = wctc[i];
                                mk.bg[i] = bg[i];     mk.bc[i] = bc[i]; }
  mk.VTg = VTg; mk.VTc = VTc;
  mk.Xg0 = Xg0; mk.Xc0 = Xc0; mk.Xg1 = Xg1; mk.Xc1 = Xc1;
  mk.ub = ub; mk.h0 = h0; mk.h1 = h1;
  mk.hisb = hisb;
  mk.hist = hist; mk.projW = projW; mk.projb = projb;
  mk.dout = d_out;
  mk.flags = flags; mk.flg = flg;
  rnn_mega<<<256, 512, 0, stream>>>(mk);
}

// Round 13
// 8156.641 us; speedup vs baseline: 1.5804x; 1.5804x over previous
//
#include <hip/hip_runtime.h>
#include <stdint.h>
#include <string.h>
#include <math.h>

// DCRNN forward on MI355X. Runtime dtype detection (fp32 vs bf16) via enc0_bg==ones.
// Phase 0/1 (weight prep, fc_his, diffusion P1..P4) = discrete kernels.
// Phase 2 (48-cell RNN) = ONE persistent mega-kernel: 256 blocks x 512 thr, 96 KB LDS
// -> 1 block/CU -> all 256 blocks co-resident. Stage barrier = single-counter arrive:
// tid==0 atomicAdd on ONE cacheline + throttled spin (round 12's 65536 distributed
// pollers flooded the TCC: MfmaUtil 2.5%, 610 GB/s -> ~60us/barrier).

using bfrag = __attribute__((__ext_vector_type__(8))) short;
using accv  = __attribute__((__ext_vector_type__(4))) float;

#define DEVI static __device__ __forceinline__

DEVI float bf2f(short x) {
  union { unsigned u; float f; } v; v.u = ((unsigned)(unsigned short)x) << 16; return v.f;
}
DEVI short f2bf(float f) {
  union { float f; unsigned u; } v; v.f = f;
  unsigned r = v.u + 0x7FFFu + ((v.u >> 16) & 1u);
  return (short)(r >> 16);
}
DEVI float ldx(const void* p, long i, int f32) {
  return f32 ? ((const float*)p)[i] : bf2f(((const short*)p)[i]);
}
DEVI void gl16(const short* g, short* l) {  // 16B direct global->LDS (dest = base + lane*16)
  __builtin_amdgcn_global_load_lds(
      (const __attribute__((address_space(1))) void*)g,
      (__attribute__((address_space(3))) void*)l, 16, 0, 0);
}

struct GP {
  const short* A;  long sA;  int lda;    // A: (M x K) row-major per batch (bf16 internal)
  const short* BT; long sBT; int ldbt;   // B transposed: (N x K) row-major per batch
  int K;
  short* C; long sC; int ldc;            // EPI 0/1 normal store
  short* CT;                             // EPI 2: plain transpose store; EPI 3: VT scatter
  const void* bias;
  const short* V0;                       // VT base (identity term) for EPI 4/5
  const int* flg;
  int outDim, oshift;
  int mtiles;                            // SWZ=1 wrapper only
  const float* h; float* hw; const float* u;
  short* xc; int inpOff;                 // EPI4: Xc target (r*h), state col offset
  short* xgs; int xgsOff;                // EPI5 persistent-X maintenance
  short* xch;
  short* nxg; short* nxc;
  const void* hsrc; long hoff;
};

// Generic tile body: BM x BN, BK k-slab, THR threads, PIPE-stage LDS pipeline.
// EPI: 0 plain; 1 bias+relu; 2 +transposed copy; 3 VT scatter; 4 gate; 5 cand.
template<int EPI, int BM, int BN, int BK, int THR, int PIPE>
DEVI void gemm_body(const GP& p, int m0, int n0, int bz, short* lds, int f32) {
  constexpr int W    = THR / 64;
  constexpr int WROW = BM / 32;
  constexpr int WCOL = (W / WROW < 1) ? 1 : W / WROW;
  constexpr int NT   = BN / (16 * WCOL);
  constexpr int CH   = BK / 8;
  constexpr int AI   = (BM * CH) / THR;
  constexpr int BI   = (BN * CH) / THR;
  constexpr int LD   = AI + BI;
  constexpr int TB   = (BM + BN) * BK;
  constexpr int ST   = BM + 8;                  // transpose LDS stride
  const int tid  = threadIdx.x;
  const int w    = tid >> 6;
  const int lane = tid & 63;
  const int quad = lane >> 4, l16 = lane & 15;
  const int rowW = (w % WROW) * 32;
  const int colW = (w / WROW) * (NT * 16);

  const short* Ab = p.A  + (long)bz * p.sA + m0 * (long)p.lda;
  const short* Bb = p.BT + (long)bz * p.sBT + n0 * (long)p.ldbt;

  accv acc[2][NT];
#pragma unroll
  for (int i = 0; i < 2; i++)
#pragma unroll
    for (int j = 0; j < NT; j++) { accv z = {0.f,0.f,0.f,0.f}; acc[i][j] = z; }

  const short* asrc[AI]; int aoff[AI];
#pragma unroll
  for (int i = 0; i < AI; i++) {
    const int s = (w*AI + i)*64 + lane;
    const int r = s / CH, c = (s % CH) ^ (r & 7);
    asrc[i] = Ab + (long)r * p.lda + c*8;
    aoff[i] = (w*AI + i)*512;
  }
  const short* bsrc[BI]; int boff[BI];
#pragma unroll
  for (int i = 0; i < BI; i++) {
    const int s = (w*BI + i)*64 + lane;
    const int r = s / CH, c = (s % CH) ^ (r & 7);
    bsrc[i] = Bb + (long)r * p.ldbt + c*8;
    boff[i] = BM*BK + (w*BI + i)*512;
  }

  const int nIter = p.K / BK;
#pragma unroll
  for (int s = 0; s < PIPE-1; ++s) {
    if (s < nIter) {
      const int kk = s * BK;
#pragma unroll
      for (int i = 0; i < AI; i++) gl16(asrc[i] + kk, &lds[s*TB + aoff[i]]);
#pragma unroll
      for (int i = 0; i < BI; i++) gl16(bsrc[i] + kk, &lds[s*TB + boff[i]]);
    }
  }

  for (int it = 0; it < nIter; ++it) {
    const int bufO = (it & (PIPE-1)) * TB;
    if (it + PIPE - 1 < nIter) {
      const int nxt = ((it + PIPE - 1) & (PIPE-1)) * TB;
      const int kk = (it + PIPE - 1) * BK;
#pragma unroll
      for (int i = 0; i < AI; i++) gl16(asrc[i] + kk, &lds[nxt + aoff[i]]);
#pragma unroll
      for (int i = 0; i < BI; i++) gl16(bsrc[i] + kk, &lds[nxt + boff[i]]);
    }
    const int rem = nIter - 1 - it;
    if (rem >= PIPE-1)   __builtin_amdgcn_s_waitcnt(0xF70 | ((PIPE-1)*LD));
    else if (rem == 2)   __builtin_amdgcn_s_waitcnt(0xF70 | (2*LD));
    else if (rem == 1)   __builtin_amdgcn_s_waitcnt(0xF70 | (1*LD));
    else                 __builtin_amdgcn_s_waitcnt(0xF70);
    asm volatile("s_barrier" ::: "memory");
#pragma unroll
    for (int ks = 0; ks < BK; ks += 32) {
      const int ch = (ks >> 3) + quad;
      bfrag fa[2];
#pragma unroll
      for (int rt = 0; rt < 2; rt++) {
        const int ar = rowW + rt*16 + l16;
        fa[rt] = *(const bfrag*)&lds[bufO + (ar*CH + (ch ^ (ar & 7))) * 8];
      }
#pragma unroll
      for (int nt = 0; nt < NT; nt++) {
        const int br = colW + nt*16 + l16;
        bfrag fb = *(const bfrag*)&lds[bufO + BM*BK + (br*CH + (ch ^ (br & 7))) * 8];
        acc[0][nt] = __builtin_amdgcn_mfma_f32_16x16x32_bf16(fa[0], fb, acc[0][nt], 0, 0, 0);
        acc[1][nt] = __builtin_amdgcn_mfma_f32_16x16x32_bf16(fa[1], fb, acc[1][nt], 0, 0, 0);
      }
    }
    asm volatile("s_barrier" ::: "memory");
  }

  if constexpr (EPI == 0 || EPI == 1 || EPI == 2) {
#pragma unroll
    for (int rt = 0; rt < 2; rt++) {
      const int rbase = m0 + rowW + rt*16 + quad*4;
#pragma unroll
      for (int nt = 0; nt < NT; nt++) {
        const int cc = n0 + colW + nt*16 + l16;
#pragma unroll
        for (int e = 0; e < 4; e++) {
          float val = acc[rt][nt][e];
          if constexpr (EPI == 1) { val += ldx(p.bias, cc, f32); val = val > 0.f ? val : 0.f; }
          p.C[(long)bz * p.sC + (long)(rbase + e) * p.ldc + cc] = f2bf(val);
        }
      }
    }
  }
  if constexpr (EPI == 2 || EPI == 3) {
    constexpr int TPC = THR / BN;            // threads per output column
    constexpr int SEG = BM / TPC;            // shorts per thread segment
    __syncthreads();
#pragma unroll
    for (int rt = 0; rt < 2; rt++)
#pragma unroll
      for (int nt = 0; nt < NT; nt++)
#pragma unroll
        for (int e = 0; e < 4; e++)
          lds[(colW + nt*16 + l16)*ST + (rowW + rt*16 + quad*4 + e)] = f2bf(acc[rt][nt][e]);
    __syncthreads();
    const int c = tid / TPC, seg = tid % TPC;
    const int cG = n0 + c;
    const short* sp = &lds[c*ST + seg*SEG];
    long dst;
    if constexpr (EPI == 3) {
      const int m  = cG >> p.oshift;
      const int o  = cG & (p.outDim - 1);
      const int bb = m0 >> 9;
      dst = ((long)((bb * p.outDim + o) * 5 + m) << 9) + (m0 & 511) + seg*SEG;
    } else {
      dst = (((long)bz << 9) + cG) * 512 + m0 + seg*SEG;
    }
    short* dp = p.CT + dst;
#pragma unroll
    for (int s2 = 0; s2 < SEG/8; s2++)
      *(bfrag*)(dp + s2*8) = *(const bfrag*)(sp + s2*8);
  }
  if constexpr (EPI == 4) {  // gate: sigmoid; o<64 -> Xc = r*h ; o>=64 -> u
#pragma unroll
    for (int rt = 0; rt < 2; rt++) {
      const int nb = m0 + rowW + rt*16 + quad*4;
#pragma unroll
      for (int nt = 0; nt < NT; nt++) {
        const int o = n0 + colW + nt*16 + l16;
        const float bv = ldx(p.bias, o, f32);
#pragma unroll
        for (int e = 0; e < 4; e++) {
          const int nn = nb + e;
          float val = acc[rt][nt][e] + bv +
                      bf2f(p.V0[(long)(bz * p.outDim + o) * 2560 + nn]);
          const float s = 1.f / (1.f + __expf(-val));
          const long bn = ((long)bz << 9) + nn;
          if (o < 64) p.xc[bn*128 + p.inpOff + o] = f2bf(s * p.h[(bn << 6) + o]);
          else        p.hw[(bn << 6) + (o - 64)] = s;
        }
      }
    }
  }
  if constexpr (EPI == 5) {  // cand: tanh; h = u*h + (1-u)*c; maintain persistent X bufs
#pragma unroll
    for (int rt = 0; rt < 2; rt++) {
      const int nb = m0 + rowW + rt*16 + quad*4;
#pragma unroll
      for (int nt = 0; nt < NT; nt++) {
        const int o = n0 + colW + nt*16 + l16;
        const float bv = ldx(p.bias, o, f32);
#pragma unroll
        for (int e = 0; e < 4; e++) {
          const int nn = nb + e;
          float val = acc[rt][nt][e] + bv +
                      bf2f(p.V0[(long)(bz * p.outDim + o) * 2560 + nn]);
          const float cth = tanhf(val);
          const long bn = ((long)bz << 9) + nn;
          const long idx = bn*64 + o;
          const float uo = p.u[idx];
          const float hn = uo * p.h[idx] + (1.f - uo) * cth;
          p.hw[idx] = hn;
          const short hb = f2bf(hn);
          if (p.xgs) p.xgs[bn*128 + p.xgsOff + o] = hb;
          if (p.nxg) { p.nxg[bn*128 + o] = hb; p.nxc[bn*128 + o] = hb; }
          if (p.hsrc != nullptr && o < 2) {
            const short hv = f2bf(ldx(p.hsrc, p.hoff + (long)bz*12288 + (long)nn*2 + o, f32));
            p.xgs[bn*128 + o] = hv;
            p.xch[bn*128 + o] = hv;
          }
        }
      }
    }
  }
}

// standalone wrapper (phases 0/1)
template<int EPI, int BM, int BN, int BK, int THR, int SWZ, int PIPE>
__global__ __launch_bounds__(THR)
void gemm_k(GP p) {
  constexpr int TB  = (BM + BN) * BK;
  constexpr int LSZ = (PIPE*TB > BN*(BM+8)) ? PIPE*TB : BN*(BM+8);
  __shared__ __align__(16) short lds[LSZ];
  int m0, n0, bz;
  if constexpr (SWZ == 1) {
    const int blk = blockIdx.x;
    bz = blk & 31;
    const int tile = blk >> 5;
    m0 = (tile % p.mtiles) * BM;
    n0 = (tile / p.mtiles) * BN;
  } else {
    m0 = blockIdx.x * BM; n0 = blockIdx.y * BN; bz = blockIdx.z;
  }
  int f32 = 0;
  if constexpr (EPI == 1 || EPI == 4 || EPI == 5) f32 = *p.flg;
  gemm_body<EPI,BM,BN,BK,THR,PIPE>(p, m0, n0, bz, lds, f32);
}

// ---- RNN mega-kernel ----

struct MK {
  const short* Pbig;
  const short* wctg[4]; const short* wctc[4];
  const void* bg[4]; const void* bc[4];
  short* VTg; short* VTc;
  short* Xg0; short* Xc0; short* Xg1; short* Xc1;
  float* ub; float* h0; float* h1;
  const short* hisb;
  const void* hist; const void* projW; const void* projb;
  void* dout;
  int* flags; const int* flg;
};

__global__ __launch_bounds__(512)
void rnn_mega(MK mk) {
  __shared__ __align__(16) short lds[49152];   // 96 KB -> 1 block/CU -> co-residency
  const int blk = blockIdx.x, tid = threadIdx.x;
  const int f32 = *mk.flg;
  int gen = 0;

  // single-counter arrive barrier: one atomicAdd + one polled cacheline per barrier.
  auto bar = [&]() {
    ++gen;
    __syncthreads();
    if (tid == 0) {
      __threadfence();  // release: prior stores visible agent-wide
      atomicAdd(&mk.flags[0], 1);
      const int target = (gen << 8);    // 256 * gen
      while (__hip_atomic_load(&mk.flags[0], __ATOMIC_RELAXED,
                               __HIP_MEMORY_SCOPE_AGENT) < target)
        __builtin_amdgcn_s_sleep(20);
      __threadfence();  // acquire: invalidate caches before reading others' data
    }
    __syncthreads();
  };

  auto cell = [&](int wi, int inpOff, float* hstate, short* XgL, short* XcL,
                  short* nxg, short* nxc, const void* hsrc, long hoff) {
    GP q;
    // g1: XgL(16384x128) @ WcatT -> VTg scatter. 1280 tiles (128mt x 10nt), 5/block.
    q = GP{}; q.A = XgL; q.lda = 128; q.BT = mk.wctg[wi]; q.ldbt = 128; q.K = 128;
    q.CT = mk.VTg; q.outDim = 128; q.oshift = 7;
    for (int i = 0; i < 5; i++) {
      const int tile = i*256 + blk;
      gemm_body<3,128,64,64,512,2>(q, (tile & 127)*128, (tile >> 7)*64, 0, lds, 0);
      __syncthreads();
    }
    bar();
    // g2: Pbig @ Ug (K=2048) fused sigmoid. 256 tiles (8mt x 32bz), 1/block, PIPE=4.
    q = GP{}; q.A = mk.Pbig; q.sA = 512*2048; q.lda = 2048;
    q.BT = mk.VTg + 512; q.sBT = 128*2560; q.ldbt = 2560; q.K = 2048;
    q.V0 = mk.VTg; q.outDim = 128; q.bias = mk.bg[wi];
    q.h = hstate; q.hw = mk.ub; q.xc = XcL; q.inpOff = inpOff;
    gemm_body<4,64,128,64,512,4>(q, (blk >> 5)*64, 0, blk & 31, lds, f32);
    bar();
    // c1: XcL @ WcT -> VTc scatter. 1280 tiles (256mt x 5nt), 5/block.
    q = GP{}; q.A = XcL; q.lda = 128; q.BT = mk.wctc[wi]; q.ldbt = 128; q.K = 128;
    q.CT = mk.VTc; q.outDim = 64; q.oshift = 6;
    for (int i = 0; i < 5; i++) {
      const int tile = i*256 + blk;
      gemm_body<3,64,64,64,512,2>(q, (tile & 255)*64, (tile >> 8)*64, 0, lds, 0);
      __syncthreads();
    }
    bar();
    // c2: Pbig @ Uc (K=2048) fused tanh + h update. 256 tiles, 1/block, PIPE=4.
    q = GP{}; q.A = mk.Pbig; q.sA = 512*2048; q.lda = 2048;
    q.BT = mk.VTc + 512; q.sBT = 64*2560; q.ldbt = 2560; q.K = 2048;
    q.V0 = mk.VTc; q.outDim = 64; q.bias = mk.bc[wi];
    q.h = hstate; q.hw = hstate; q.u = mk.ub;
    q.xgs = XgL; q.xgsOff = inpOff; q.xch = XcL;
    q.nxg = nxg; q.nxc = nxc; q.hsrc = hsrc; q.hoff = hoff;
    gemm_body<5,64,64,64,512,4>(q, (blk >> 5)*64, 0, blk & 31, lds, f32);
    bar();
  };

  // encoder
  for (int t = 0; t < 12; t++) {
    cell(0, 2, mk.h0, mk.Xg0, mk.Xc0, mk.Xg1, mk.Xc1,
         (t < 11) ? mk.hist : nullptr, (long)(t + 1) * 1024);
    cell(1, 64, mk.h1, mk.Xg1, mk.Xc1, nullptr, nullptr, nullptr, 0);
  }
  // his_add
  for (int i = blk*512 + tid; i < 1048576; i += 131072) {
    const int row = i >> 6, o = i & 63;
    const float v = bf2f(mk.hisb[i]);
    const float a = mk.h0[i] + v, b = mk.h1[i] + v;
    mk.h0[i] = a; mk.h1[i] = b;
    mk.Xg0[(long)row*128 + 1 + o]  = f2bf(a);
    mk.Xg1[(long)row*128 + 64 + o] = f2bf(b);
    if (o == 0) { mk.Xg0[(long)row*128] = 0; mk.Xc0[(long)row*128] = 0; }
  }
  bar();
  // decoder
  const int lane = tid & 63;
  const int wid  = (blk*512 + tid) >> 6;   // 0..2047
  for (int t = 0; t < 12; t++) {
    cell(2, 1, mk.h0, mk.Xg0, mk.Xc0, mk.Xg1, mk.Xc1, nullptr, 0);
    cell(3, 64, mk.h1, mk.Xg1, mk.Xc1, nullptr, nullptr, nullptr, 0);
    // proj: wave-per-row
    for (int row = wid; row < 16384; row += 2048) {
      float v = mk.h1[((long)row << 6) + lane] * ldx(mk.projW, lane, f32);
      for (int off = 32; off > 0; off >>= 1) v += __shfl_down(v, off, 64);
      if (lane == 0) {
        const float s = v + ldx(mk.projb, 0, f32);
        if (f32) ((float*)mk.dout)[row*12 + t] = s;
        else     ((short*)mk.dout)[row*12 + t] = f2bf(s);
        const short o = f2bf(s);
        mk.Xg0[(long)row*128] = o;
        mk.Xc0[(long)row*128] = o;
      }
    }
    bar();
  }
}

// ---- small kernels ----

__global__ void detect_k(const short* bg0, int* flag) {
  if (threadIdx.x == 0 && blockIdx.x == 0)
    *flag = (bg0[0] == (short)0x3F80) ? 0 : 1;
}

__global__ void rowsum_inv(const void* adj, const int* flg, float* rsi) {
  const int f32 = *flg;
  const int wid  = (blockIdx.x * 256 + threadIdx.x) >> 6;
  const int lane = threadIdx.x & 63;
  const long base = (long)wid * 512;
  float s = 0.f;
  for (int j = lane; j < 512; j += 64) s += ldx(adj, base + j, f32);
  for (int off = 32; off > 0; off >>= 1) s += __shfl_down(s, off, 64);
  if (lane == 0) rsi[wid] = 1.f / (1.f + s);
}

__global__ void colsum_inv(const void* adj, const int* flg, float* csi) {
  const int f32 = *flg;
  const int i = blockIdx.x * 256 + threadIdx.x;
  const int b = i >> 9, col = i & 511;
  const long base = (long)b * 262144 + col;
  float s = 1.f;
  for (int j = 0; j < 512; j++) s += ldx(adj, base + (long)j * 512, f32);
  csi[i] = 1.f / s;
}

__global__ __launch_bounds__(256)
void build_a(const void* adj, const int* flg, const float* rsi, const float* csi,
             short* Pbig, short* A1T, short* A2) {
  const int f32 = *flg;
  __shared__ __align__(16) float t[64 * 65];
  const int b = blockIdx.z, ti = blockIdx.x, tj = blockIdx.y;
  const int tid = threadIdx.x;
  const int r = tid >> 2, cs = (tid & 3) * 16;
  const long base = (long)b * 262144 + (long)(ti*64 + r) * 512 + tj*64 + cs;
#pragma unroll
  for (int j = 0; j < 16; j++) t[r*65 + cs + j] = ldx(adj, base + j, f32);
  __syncthreads();
  {
    const int gi = ti*64 + r;
    const float inv = rsi[b*512 + gi];
    short o[16];
#pragma unroll
    for (int j = 0; j < 16; j++) {
      const int gj = tj*64 + cs + j;
      o[j] = f2bf((t[r*65 + cs + j] + (gi == gj ? 1.f : 0.f)) * inv);
    }
    short* dp = Pbig + ((long)(b*512 + gi) << 11) + tj*64 + cs;
    bfrag v0 = {o[0],o[1],o[2],o[3],o[4],o[5],o[6],o[7]};
    bfrag v1 = {o[8],o[9],o[10],o[11],o[12],o[13],o[14],o[15]};
    *(bfrag*)dp = v0; *(bfrag*)(dp + 8) = v1;
  }
  {
    const int y = tj*64 + r;
    const float invc = csi[b*512 + y];
    short o1[16], o2[16];
#pragma unroll
    for (int j = 0; j < 16; j++) {
      const int x = ti*64 + cs + j;
      const float av = t[(cs + j)*65 + r];
      const float d = (x == y) ? 1.f : 0.f;
      o1[j] = f2bf((av + d) * rsi[b*512 + x]);
      o2[j] = f2bf((av + d) * invc);
    }
    short* d1 = A1T + ((long)(b*512 + y) << 9) + ti*64 + cs;
    short* d2 = A2  + ((long)(b*512 + y) << 9) + ti*64 + cs;
    bfrag a0 = {o1[0],o1[1],o1[2],o1[3],o1[4],o1[5],o1[6],o1[7]};
    bfrag a1 = {o1[8],o1[9],o1[10],o1[11],o1[12],o1[13],o1[14],o1[15]};
    bfrag b0 = {o2[0],o2[1],o2[2],o2[3],o2[4],o2[5],o2[6],o2[7]};
    bfrag b1 = {o2[8],o2[9],o2[10],o2[11],o2[12],o2[13],o2[14],o2[15]};
    *(bfrag*)d1 = a0; *(bfrag*)(d1 + 8) = a1;
    *(bfrag*)d2 = b0; *(bfrag*)(d2 + 8) = b1;
  }
}

__global__ void build_wcat(const void* W, const int* flg, short* WT, int f, int out) {
  const int f32 = *flg;
  const int i = blockIdx.x * 256 + threadIdx.x;
  if (i >= 5 * out * 128) return;
  const int feat = i & 127;
  const int mo = i >> 7;
  const int m = mo / out;
  const int o = mo - m * out;
  float v = 0.f;
  if (feat < f) {
    const long base = (long)feat * 5 * out;
    const float w0 = ldx(W, base + 0*out + o, f32);
    const float w1 = ldx(W, base + 1*out + o, f32);
    const float w2 = ldx(W, base + 2*out + o, f32);
    const float w3 = ldx(W, base + 3*out + o, f32);
    const float w4 = ldx(W, base + 4*out + o, f32);
    v = (m == 0) ? (w0 - w2) : (m == 1) ? (w1 - w4) : (m == 2) ? 2.f*w2
      : (m == 3) ? w3 : 2.f*w4;
  }
  WT[(long)mo * 128 + feat] = f2bf(v);
}

__global__ void build_fc1T(const void* W, const int* flg, short* WT) {
  const int f32 = *flg;
  const int i = blockIdx.x * 256 + threadIdx.x;
  const int o = i >> 7, k = i & 127;
  WT[i] = (k < 96) ? f2bf(ldx(W, (long)k*256 + o, f32)) : (short)0;
}
__global__ void build_fc2T(const void* W, const int* flg, short* WT) {
  const int f32 = *flg;
  const int i = blockIdx.x * 256 + threadIdx.x;
  const int o = i >> 8, k = i & 255;
  WT[i] = f2bf(ldx(W, (long)k*64 + o, f32));
}
__global__ void pack_hid(const void* hd, const int* flg, short* hp) {
  const int f32 = *flg;
  const int i = blockIdx.x * 256 + threadIdx.x;
  const int row = i >> 7, k = i & 127;
  hp[i] = (k < 96) ? f2bf(ldx(hd, (long)row*96 + k, f32)) : (short)0;
}

__global__ void seed_hist(const void* hist, const int* flg, short* Xg0, short* Xc0) {
  const int f32 = *flg;
  const int i = blockIdx.x * 256 + threadIdx.x;
  const int row = i >> 1, c = i & 1;
  const short v = f2bf(ldx(hist, (long)(row >> 9)*12288 + (long)(row & 511)*2 + c, f32));
  Xg0[(long)row*128 + c] = v;
  Xc0[(long)row*128 + c] = v;
}

extern "C" void kernel_launch(void* const* d_in, const int* in_sizes, int n_in,
                              void* d_out, int out_size, void* d_ws, size_t ws_size,
                              hipStream_t stream) {
  (void)in_sizes; (void)n_in; (void)out_size;
  const void* hist   = d_in[0];
  const void* hidden = d_in[1];
  const void* adj    = d_in[2];
  const void* Wg[4] = {d_in[3], d_in[7],  d_in[11], d_in[15]};
  const void* bg[4] = {d_in[4], d_in[8],  d_in[12], d_in[16]};
  const void* Wc[4] = {d_in[5], d_in[9],  d_in[13], d_in[17]};
  const void* bc[4] = {d_in[6], d_in[10], d_in[14], d_in[18]};
  const void* projW = d_in[19];
  const void* projb = d_in[20];
  const void* fc1W  = d_in[21];
  const void* fc1b  = d_in[22];
  const void* fc2W  = d_in[23];
  const void* fc2b  = d_in[24];

  char* wp = (char*)d_ws;
  auto alloc = [&](size_t bytes) { char* r = wp; wp += (bytes + 255) & ~(size_t)255; return r; };
  short* Pbig = (short*)alloc(32ull*512*2048*2);
  float* ub   = (float*)alloc(16384ull*64*4);
  float* h0   = (float*)alloc(16384ull*64*4);
  float* h1   = (float*)alloc(16384ull*64*4);
  short* hisb = (short*)alloc(16384ull*64*2);
  short* wctg[4]; for (int i = 0; i < 4; i++) wctg[i] = (short*)alloc(640*128*2);
  short* wctc[4]; for (int i = 0; i < 4; i++) wctc[i] = (short*)alloc(320*128*2);
  float* rsi = (float*)alloc(16384*4);
  float* csi = (float*)alloc(16384*4);
  int*   flg = (int*)alloc(256);
  int*   flags = (int*)alloc(2048);
  char* ubase = wp;
  short* hidp = (short*)ubase;
  short* mid  = (short*)(ubase + 4194304);
  short* fc1T = (short*)(ubase + 4194304 + 8388608);
  short* fc2T = (short*)(ubase + 4194304 + 8388608 + 65536);
  short* A1T  = (short*)ubase;
  short* A2   = (short*)(ubase + 16777216);
  short* P3T  = (short*)(ubase + 33554432);
  short* VTg  = (short*)ubase;
  short* VTc  = (short*)(ubase + 20971520);
  short* Xg0  = (short*)(ubase + 31457280);
  short* Xc0  = (short*)(ubase + 35651584);
  short* Xg1  = (short*)(ubase + 39845888);
  short* Xc1  = (short*)(ubase + 44040192);
  const size_t need = (size_t)(ubase - (char*)d_ws) + 48234496 + 2097152;
  if (ws_size < need) return;

  detect_k<<<1, 64, 0, stream>>>((const short*)bg[0], flg);
  (void)hipMemsetAsync(h0, 0, 16384ull*64*4, stream);
  (void)hipMemsetAsync(h1, 0, 16384ull*64*4, stream);
  (void)hipMemsetAsync(flags, 0, 2048, stream);

  // ---- phase 0: weight prep + fc_his ----
  const int fdim[4] = {66, 128, 65, 128};
  for (int i = 0; i < 4; i++) {
    build_wcat<<<320, 256, 0, stream>>>(Wg[i], flg, wctg[i], fdim[i], 128);
    build_wcat<<<160, 256, 0, stream>>>(Wc[i], flg, wctc[i], fdim[i], 64);
  }
  build_fc1T<<<128, 256, 0, stream>>>(fc1W, flg, fc1T);
  build_fc2T<<<64, 256, 0, stream>>>(fc2W, flg, fc2T);
  pack_hid<<<8192, 256, 0, stream>>>(hidden, flg, hidp);

  GP p;
  p = GP{}; p.A = hidp; p.lda = 128; p.BT = fc1T; p.ldbt = 128; p.K = 128;
  p.C = mid; p.ldc = 256; p.bias = fc1b; p.flg = flg;
  gemm_k<1,128,64,64,256,0,2><<<dim3(128, 4, 1), 256, 0, stream>>>(p);
  p = GP{}; p.A = mid; p.lda = 256; p.BT = fc2T; p.ldbt = 256; p.K = 256;
  p.C = hisb; p.ldc = 64; p.bias = fc2b; p.flg = flg;
  gemm_k<1,128,64,64,256,0,2><<<dim3(128, 1, 1), 256, 0, stream>>>(p);

  // ---- phase 1: diffusion matrices ----
  rowsum_inv<<<4096, 256, 0, stream>>>(adj, flg, rsi);
  colsum_inv<<<64, 256, 0, stream>>>(adj, flg, csi);
  build_a<<<dim3(8, 8, 32), 256, 0, stream>>>(adj, flg, rsi, csi, Pbig, A1T, A2);

  p = GP{}; p.A = Pbig; p.sA = 512*2048; p.lda = 2048;
  p.BT = A1T; p.sBT = 512*512; p.ldbt = 512; p.K = 512;
  p.C = Pbig + 512; p.sC = 512*2048; p.ldc = 2048; p.flg = flg;
  gemm_k<0,128,64,64,256,0,2><<<dim3(4, 8, 32), 256, 0, stream>>>(p);
  p = GP{}; p.A = A2; p.sA = 512*512; p.lda = 512;
  p.BT = A1T; p.sBT = 512*512; p.ldbt = 512; p.K = 512;
  p.C = Pbig + 1024; p.sC = 512*2048; p.ldc = 2048; p.CT = P3T; p.flg = flg;
  gemm_k<2,128,64,64,256,0,2><<<dim3(4, 8, 32), 256, 0, stream>>>(p);
  p = GP{}; p.A = A2; p.sA = 512*512; p.lda = 512;
  p.BT = P3T; p.sBT = 512*512; p.ldbt = 512; p.K = 512;
  p.C = Pbig + 1536; p.sC = 512*2048; p.ldc = 2048; p.flg = flg;
  gemm_k<0,128,64,64,256,0,2><<<dim3(4, 8, 32), 256, 0, stream>>>(p);

  // ---- phase 2: persistent RNN mega-kernel ----
  (void)hipMemsetAsync(Xg0, 0, 4ull*4194304, stream);
  seed_hist<<<128, 256, 0, stream>>>(hist, flg, Xg0, Xc0);

  MK mk{};
  mk.Pbig = Pbig;
  for (int i = 0; i < 4; i++) { mk.wctg[i] = wctg[i]; mk.wctc[i] = wctc[i];
                                mk.bg[i] = bg[i];     mk.bc[i] = bc[i]; }
  mk.VTg = VTg; mk.VTc = VTc;
  mk.Xg0 = Xg0; mk.Xc0 = Xc0; mk.Xg1 = Xg1; mk.Xc1 = Xc1;
  mk.ub = ub; mk.h0 = h0; mk.h1 = h1;
  mk.hisb = hisb;
  mk.hist = hist; mk.projW = projW; mk.projb = projb;
  mk.dout = d_out;
  mk.flags = flags; mk.flg = flg;
  rnn_mega<<<256, 512, 0, stream>>>(mk);
}